// Round 15
// baseline (896.866 us; speedup 1.0000x reference)
//
#include <hip/hip_runtime.h>
#include <hip/hip_bf16.h>

typedef __attribute__((ext_vector_type(8))) short short8;
typedef __attribute__((ext_vector_type(4))) float f32x4;

#define NQ 95
#define HDIM 512
#define RBF 6
#define BM 128

static __device__ __forceinline__ unsigned short f2bf(float f){
  unsigned u = __float_as_uint(f);
  u += 0x7FFF + ((u >> 16) & 1);          // round-to-nearest-even
  return (unsigned short)(u >> 16);
}
static __device__ __forceinline__ float swishf(float z){
  float e = __expf(-z);
  return z * __builtin_amdgcn_rcpf(1.0f + e);
}

// ---------------------------------------------------------------------------
// P0[v][n] = sum_k emb[v][k] * W_lin[k][n] + b_lin[n];  P1: second 512-block
// ---------------------------------------------------------------------------
__global__ __launch_bounds__(512) void prep_tables(
    const float* __restrict__ emb, const float* __restrict__ W_lin,
    const float* __restrict__ b_lin, float* __restrict__ P0,
    float* __restrict__ P1)
{
  __shared__ float sE[HDIM];
  const int v   = blockIdx.x % NQ;
  const int tab = blockIdx.x / NQ;
  const int t   = threadIdx.x;
  sE[t] = emb[v*HDIM + t];
  __syncthreads();
  const float* W = W_lin + (size_t)tab * HDIM * HDIM + t;
  float a = tab ? 0.f : b_lin[t];
  #pragma unroll 8
  for (int k = 0; k < HDIM; ++k)
    a += sE[k] * W[(size_t)k * HDIM];
  (tab ? P1 : P0)[v*HDIM + t] = a;
}

// ---------------------------------------------------------------------------
// W2T[n][k] = bf16(W_lin[1024+k][n])   (512x512 bf16, n-major)
// ---------------------------------------------------------------------------
__global__ __launch_bounds__(256) void prep_w2t(
    const float* __restrict__ W_lin, unsigned short* __restrict__ W2T)
{
  const int idx = blockIdx.x * 256 + threadIdx.x;
  const int n  = idx >> 6;
  const int kb = (idx & 63) * 8;
  const float* W2 = W_lin + (size_t)1024 * HDIM;
  unsigned p[4];
  #pragma unroll
  for (int c = 0; c < 4; ++c){
    unsigned lo = f2bf(W2[(size_t)(kb + 2*c    ) * HDIM + n]);
    unsigned hi = f2bf(W2[(size_t)(kb + 2*c + 1) * HDIM + n]);
    p[c] = lo | (hi << 16);
  }
  uint4 o; o.x = p[0]; o.y = p[1]; o.z = p[2]; o.w = p[3];
  *(uint4*)(W2T + (size_t)n * HDIM + kb) = o;
}

// ---------------------------------------------------------------------------
// R10-structure fused kernel. DIAGNOSTIC ROUND: grid doubled via
// blockIdx.x % nblk (each tile computed/stored twice, identical values) so
// this dispatch outlasts harness fill kernels and exposes its counters.
// ---------------------------------------------------------------------------
__global__ __launch_bounds__(1024, 4) void fused_edge(
    const int* __restrict__ xv, const float* __restrict__ rbf,
    const int* __restrict__ ei, const int* __restrict__ ej,
    const float* __restrict__ W0, const float* __restrict__ b0,
    const float* __restrict__ W1,
    const float* __restrict__ P0, const float* __restrict__ P1,
    const unsigned short* __restrict__ W2T,
    float* __restrict__ out, int E, int nblk)
{
  __shared__ unsigned short sA[BM * HDIM];   // 128 KB
  __shared__ float sRbf[BM * RBF];
  __shared__ int sXi[BM], sXj[BM];

  const int t  = threadIdx.x;
  const int eb = (blockIdx.x % nblk) * BM;
  const int me = min(BM, E - eb);

  // ---- stage rbf rows (128*6 = 192 float4) + node-type indices ----
  if (t < 192){
    float4 v = make_float4(0.f, 0.f, 0.f, 0.f);
    size_t gi  = (size_t)eb * RBF + (size_t)t * 4;
    size_t lim = (size_t)E * RBF;
    if (gi + 4 <= lim) v = *(const float4*)(rbf + gi);
    else {
      float* pv = (float*)&v;
      for (int c = 0; c < 4; ++c) if (gi + c < lim) pv[c] = rbf[gi + c];
    }
    *(float4*)(sRbf + t*4) = v;
  } else if (t >= 256 && t < 384){
    int q = t - 256;
    int xi = 0, xj = 0;
    int e = eb + q;
    if (e < E){ xi = xv[ei[e]]; xj = xv[ej[e]]; }
    sXi[q] = xi; sXj[q] = xj;
  }

  // phase-1 assignment: 256 col-pairs x 4 row-quarters (32 rows each)
  const int cp = t & 255;          // k-pair: cols 2cp, 2cp+1
  const int q4 = t >> 8;           // rows q4*32 .. q4*32+31
  float2 w0c[RBF];
  #pragma unroll
  for (int r = 0; r < RBF; ++r) w0c[r] = *(const float2*)(W0 + r*HDIM + 2*cp);
  float2 bb = *(const float2*)(b0 + 2*cp);

  __syncthreads();

  char* sAb = (char*)sA;
  // ---- phase 1: rbf0 tile ----
  {
    const int swz_t = 4 * cp;
    const int m0 = q4 * 32;
    #pragma unroll 2
    for (int mm = 0; mm < 32; ++mm){
      const int m = m0 + mm;
      float2 ra = *(const float2*)(sRbf + m*RBF);
      float2 rb = *(const float2*)(sRbf + m*RBF + 2);
      float2 rc = *(const float2*)(sRbf + m*RBF + 4);
      float z0 = bb.x, z1 = bb.y;
      z0 += ra.x*w0c[0].x + ra.y*w0c[1].x + rb.x*w0c[2].x
          + rb.y*w0c[3].x + rc.x*w0c[4].x + rc.y*w0c[5].x;
      z1 += ra.x*w0c[0].y + ra.y*w0c[1].y + rb.x*w0c[2].y
          + rb.y*w0c[3].y + rc.x*w0c[4].y + rc.y*w0c[5].y;
      unsigned pk = (unsigned)f2bf(swishf(z0)) | ((unsigned)f2bf(swishf(z1)) << 16);
      *(unsigned*)(sAb + (m*1024 + (swz_t ^ ((m & 7) << 4)))) = pk;
    }
  }
  __syncthreads();

  // ---- phase 2: MFMA K-loop (wave tile: 128 rows x 32 cols) ----
  const int lane  = t & 63;
  const int w     = t >> 6;        // 0..15
  const int nbase = w * 32;
  const int rlo   = lane & 15;
  const int kg    = lane >> 4;

  f32x4 acc[8][2];
  #pragma unroll
  for (int a = 0; a < 8; ++a)
    #pragma unroll
    for (int b = 0; b < 2; ++b) acc[a][b] = f32x4{0.f, 0.f, 0.f, 0.f};

  const unsigned short* bp0 = W2T + (size_t)(nbase + rlo)*HDIM + kg*8;
  const unsigned short* bp1 = bp0 + (size_t)16*HDIM;

  for (int ks = 0; ks < 16; ++ks){
    short8 b0r = *(const short8*)(bp0 + ks*32);
    short8 b1r = *(const short8*)(bp1 + ks*32);
    #pragma unroll
    for (int mt = 0; mt < 8; ++mt){
      int row = mt*16 + rlo;
      int off = row*1024 + ((ks*64 + kg*16) ^ ((row & 7) << 4));
      short8 af = *(const short8*)(sAb + off);
      acc[mt][0] = __builtin_amdgcn_mfma_f32_16x16x32_bf16(af, b0r, acc[mt][0], 0, 0, 0);
      acc[mt][1] = __builtin_amdgcn_mfma_f32_16x16x32_bf16(af, b1r, acc[mt][1], 0, 0, 0);
    }
  }

  __syncthreads();   // all waves done reading the A-tile -> sA is dead

  // ---- epilogue: 4 chunks x 32 rows; acc-repack; coalesced sweep ----
  float* sF = (float*)sA;              // 32 x 512 f32 = 64 KB (in dead A-tile)
  const int n0  = (4*t) & (HDIM - 1);  // fixed 4 output columns per thread
  const int rad = t >> 7;              // 0..7 (8 rows per sweep pass)

  f32x4 w1v[RBF];
  #pragma unroll
  for (int r = 0; r < RBF; ++r) w1v[r] = *(const f32x4*)(W1 + r*HDIM + n0);
  float* __restrict__ out2 = out + (size_t)E * HDIM;

  #pragma unroll
  for (int c = 0; c < 4; ++c){
    if (c) __syncthreads();            // prev sweep done reading sF
    // scatter: raw acc of rows 32c..32c+31 into sF (fragment layout write)
    #pragma unroll
    for (int mi = 0; mi < 2; ++mi){
      #pragma unroll
      for (int r = 0; r < 4; ++r){
        const int lr = mi*16 + kg*4 + r;       // local row 0..31
        #pragma unroll
        for (int nt = 0; nt < 2; ++nt){
          const int n = nbase + nt*16 + rlo;
          sF[lr*HDIM + n] = acc[2*c + mi][nt][r];
        }
      }
    }
    __syncthreads();
    // sweep: thread owns 4 contiguous cols of 8 rows per pass
    #pragma unroll
    for (int j = 0; j < 4; ++j){
      const int lm = j*8 + rad;
      const int m  = c*32 + lm;
      const bool valid = (m < me);
      const int xi = sXi[m], xj = sXj[m];      // wave-uniform row indices
      f32x4 a  = *(const f32x4*)(sF + lm*HDIM + n0);
      f32x4 p0 = *(const f32x4*)(P0 + (size_t)xi*HDIM + n0);
      f32x4 p1 = *(const f32x4*)(P1 + (size_t)xj*HDIM + n0);
      f32x4 f  = (a + p0) + p1;
      f32x4 e1;
      e1.x = swishf(f.x); e1.y = swishf(f.y);
      e1.z = swishf(f.z); e1.w = swishf(f.w);
      float2 ra = *(const float2*)(sRbf + m*RBF);
      float2 rb = *(const float2*)(sRbf + m*RBF + 2);
      float2 rc = *(const float2*)(sRbf + m*RBF + 4);
      f32x4 g;
      g.x = ra.x*w1v[0].x + ra.y*w1v[1].x + rb.x*w1v[2].x
          + rb.y*w1v[3].x + rc.x*w1v[4].x + rc.y*w1v[5].x;
      g.y = ra.x*w1v[0].y + ra.y*w1v[1].y + rb.x*w1v[2].y
          + rb.y*w1v[3].y + rc.x*w1v[4].y + rc.y*w1v[5].y;
      g.z = ra.x*w1v[0].z + ra.y*w1v[1].z + rb.x*w1v[2].z
          + rb.y*w1v[3].z + rc.x*w1v[4].z + rc.y*w1v[5].z;
      g.w = ra.x*w1v[0].w + ra.y*w1v[1].w + rb.x*w1v[2].w
          + rb.y*w1v[3].w + rc.x*w1v[4].w + rc.y*w1v[5].w;
      f32x4 e2 = g * e1;
      if (valid){
        const size_t orow = (size_t)(eb + m) * HDIM + n0;
        *(f32x4*)(out  + orow) = e1;
        *(f32x4*)(out2 + orow) = e2;
      }
    }
  }
}

// ---------------------------------------------------------------------------
extern "C" void kernel_launch(void* const* d_in, const int* in_sizes, int n_in,
                              void* d_out, int out_size, void* d_ws, size_t ws_size,
                              hipStream_t stream) {
  const int*   xv    = (const int*)  d_in[0];
  const float* rbf   = (const float*)d_in[1];
  const int*   ei    = (const int*)  d_in[2];
  const int*   ej    = (const int*)  d_in[3];
  const float* emb   = (const float*)d_in[4];
  const float* W0    = (const float*)d_in[5];
  const float* b0    = (const float*)d_in[6];
  const float* W_lin = (const float*)d_in[7];
  const float* b_lin = (const float*)d_in[8];
  const float* W1    = (const float*)d_in[9];
  float* out = (float*)d_out;

  const int E = in_sizes[2];

  float* P0 = (float*)d_ws;
  float* P1 = P0 + NQ * HDIM;
  unsigned short* W2T = (unsigned short*)(P1 + NQ * HDIM);

  prep_tables<<<2 * NQ, 512, 0, stream>>>(emb, W_lin, b_lin, P0, P1);
  prep_w2t<<<(HDIM * (HDIM/8)) / 256, 256, 0, stream>>>(W_lin, W2T);

  const int nblk = (E + BM - 1) / BM;
  // DIAGNOSTIC: grid doubled so this dispatch appears in rocprof top-k.
  fused_edge<<<2 * nblk, 1024, 0, stream>>>(xv, rbf, ei, ej, W0, b0, W1,
                                            P0, P1, W2T, out, E, nblk);
}

// Round 17
// 593.476 us; speedup vs baseline: 1.5112x; 1.5112x over previous
//
#include <hip/hip_runtime.h>
#include <hip/hip_bf16.h>

typedef __attribute__((ext_vector_type(8))) short short8;
typedef __attribute__((ext_vector_type(4))) float f32x4;

#define NQ 95
#define HDIM 512
#define RBF 6
#define BM 64
#define SFS 264   // e1/e2 plane row stride (f32), 16B-aligned, bank-spread

static __device__ __forceinline__ unsigned short f2bf(float f){
  unsigned u = __float_as_uint(f);
  u += 0x7FFF + ((u >> 16) & 1);          // round-to-nearest-even
  return (unsigned short)(u >> 16);
}
static __device__ __forceinline__ float swishf(float z){
  float e = __expf(-z);
  return z * __builtin_amdgcn_rcpf(1.0f + e);
}

// ---------------------------------------------------------------------------
// P0[v][n] = sum_k emb[v][k] * W_lin[k][n] + b_lin[n];  P1: second 512-block
// ---------------------------------------------------------------------------
__global__ __launch_bounds__(512) void prep_tables(
    const float* __restrict__ emb, const float* __restrict__ W_lin,
    const float* __restrict__ b_lin, float* __restrict__ P0,
    float* __restrict__ P1)
{
  __shared__ float sE[HDIM];
  const int v   = blockIdx.x % NQ;
  const int tab = blockIdx.x / NQ;
  const int t   = threadIdx.x;
  sE[t] = emb[v*HDIM + t];
  __syncthreads();
  const float* W = W_lin + (size_t)tab * HDIM * HDIM + t;
  float a = tab ? 0.f : b_lin[t];
  #pragma unroll 8
  for (int k = 0; k < HDIM; ++k)
    a += sE[k] * W[(size_t)k * HDIM];
  (tab ? P1 : P0)[v*HDIM + t] = a;
}

// ---------------------------------------------------------------------------
// W2T[n][k] = bf16(W_lin[1024+k][n])   (512x512 bf16, n-major)
// ---------------------------------------------------------------------------
__global__ __launch_bounds__(256) void prep_w2t(
    const float* __restrict__ W_lin, unsigned short* __restrict__ W2T)
{
  const int idx = blockIdx.x * 256 + threadIdx.x;
  const int n  = idx >> 6;
  const int kb = (idx & 63) * 8;
  const float* W2 = W_lin + (size_t)1024 * HDIM;
  unsigned p[4];
  #pragma unroll
  for (int c = 0; c < 4; ++c){
    unsigned lo = f2bf(W2[(size_t)(kb + 2*c    ) * HDIM + n]);
    unsigned hi = f2bf(W2[(size_t)(kb + 2*c + 1) * HDIM + n]);
    p[c] = lo | (hi << 16);
  }
  uint4 o; o.x = p[0]; o.y = p[1]; o.z = p[2]; o.w = p[3];
  *(uint4*)(W2T + (size_t)n * HDIM + kb) = o;
}

// ---------------------------------------------------------------------------
// Fused main kernel: 512 threads (8 waves), BM=64 edges, N split in halves
// (block owns 256 cols; 2 blocks/CU -> cross-block phase overlap, R15 diag).
//   phase 1: A = bf16(swish(rbf@W0+b0)) [64x512] LDS (XOR swizzle)
//   phase 2: acc = A @ W2T slice, wave tile 64 rows x 32 cols (acc[4][2])
//   epilogue (R5-validated scheme): per 16-row chunk, scatter computes
//     e1 AND e2 in MFMA fragment layout (g via scalar w1c[r][nt]) into TWO
//     padded LDS planes; sweeps are PURE COPIES emitting 1KB-contiguous
//     f32x4 lines. No g-math outside the fragment layout (3x e2-fail lesson).
// ---------------------------------------------------------------------------
__global__ __launch_bounds__(512, 4) void fused_edge(
    const int* __restrict__ xv, const float* __restrict__ rbf,
    const int* __restrict__ ei, const int* __restrict__ ej,
    const float* __restrict__ W0, const float* __restrict__ b0,
    const float* __restrict__ W1,
    const float* __restrict__ P0, const float* __restrict__ P1,
    const unsigned short* __restrict__ W2T,
    float* __restrict__ out, int E)
{
  __shared__ unsigned short sA[BM * HDIM];   // 64 KB (planes live here later)
  __shared__ float sRbf[BM * RBF];
  __shared__ int sXi[BM], sXj[BM];

  const int t     = threadIdx.x;
  const int tile  = blockIdx.x >> 1;
  const int nhalf = blockIdx.x & 1;          // this block's 256-col half
  const int eb    = tile * BM;
  const int me    = min(BM, E - eb);

  // ---- stage rbf rows + node-type indices ----
  if (t < 96){
    float4 v = make_float4(0.f, 0.f, 0.f, 0.f);
    size_t gi  = (size_t)eb * RBF + (size_t)t * 4;
    size_t lim = (size_t)E * RBF;
    if (gi + 4 <= lim) v = *(const float4*)(rbf + gi);
    else {
      float* pv = (float*)&v;
      for (int c = 0; c < 4; ++c) if (gi + c < lim) pv[c] = rbf[gi + c];
    }
    *(float4*)(sRbf + t*4) = v;
  } else if (t >= 128 && t < 192){
    int q = t - 128;
    int xi = 0, xj = 0;
    int e = eb + q;
    if (e < E){ xi = xv[ei[e]]; xj = xv[ej[e]]; }
    sXi[q] = xi; sXj[q] = xj;
  }

  // phase-1 assignment: 256 col-pairs x 2 row-halves (full K=512)
  const int cp   = t & 255;
  const int half = t >> 8;
  float2 w0c[RBF];
  #pragma unroll
  for (int r = 0; r < RBF; ++r) w0c[r] = *(const float2*)(W0 + r*HDIM + 2*cp);
  float2 bb = *(const float2*)(b0 + 2*cp);

  __syncthreads();

  char* sAb = (char*)sA;
  // ---- phase 1: rbf0 tile ----
  {
    const int swz_t = 4 * cp;
    const int m0 = half * 32;
    #pragma unroll 2
    for (int mm = 0; mm < 32; ++mm){
      const int m = m0 + mm;
      float2 ra = *(const float2*)(sRbf + m*RBF);
      float2 rb = *(const float2*)(sRbf + m*RBF + 2);
      float2 rc = *(const float2*)(sRbf + m*RBF + 4);
      float z0 = bb.x, z1 = bb.y;
      z0 += ra.x*w0c[0].x + ra.y*w0c[1].x + rb.x*w0c[2].x
          + rb.y*w0c[3].x + rc.x*w0c[4].x + rc.y*w0c[5].x;
      z1 += ra.x*w0c[0].y + ra.y*w0c[1].y + rb.x*w0c[2].y
          + rb.y*w0c[3].y + rc.x*w0c[4].y + rc.y*w0c[5].y;
      unsigned pk = (unsigned)f2bf(swishf(z0)) | ((unsigned)f2bf(swishf(z1)) << 16);
      *(unsigned*)(sAb + (m*1024 + (swz_t ^ ((m & 7) << 4)))) = pk;
    }
  }
  __syncthreads();

  // ---- phase 2: MFMA K-loop (wave tile: 64 rows x 32 cols of our half) ----
  const int lane  = t & 63;
  const int w     = t >> 6;        // 0..7
  const int ncol0 = w * 32;        // block-local col base
  const int rlo   = lane & 15;
  const int kg    = lane >> 4;

  f32x4 acc[4][2];
  #pragma unroll
  for (int a = 0; a < 4; ++a){
    acc[a][0] = f32x4{0.f,0.f,0.f,0.f};
    acc[a][1] = f32x4{0.f,0.f,0.f,0.f};
  }

  const unsigned short* bp0 = W2T + (size_t)(nhalf*256 + ncol0 + rlo)*HDIM + kg*8;
  const unsigned short* bp1 = bp0 + (size_t)16*HDIM;

  for (int ks = 0; ks < 16; ++ks){
    short8 b0r = *(const short8*)(bp0 + ks*32);
    short8 b1r = *(const short8*)(bp1 + ks*32);
    #pragma unroll
    for (int mt = 0; mt < 4; ++mt){
      int row = mt*16 + rlo;
      int off = row*1024 + ((ks*64 + kg*16) ^ ((row & 7) << 4));
      short8 af = *(const short8*)(sAb + off);
      acc[mt][0] = __builtin_amdgcn_mfma_f32_16x16x32_bf16(af, b0r, acc[mt][0], 0, 0, 0);
      acc[mt][1] = __builtin_amdgcn_mfma_f32_16x16x32_bf16(af, b1r, acc[mt][1], 0, 0, 0);
    }
  }

  __syncthreads();   // all waves done reading A-tile -> sA reusable

  // ---- epilogue: R5 scheme. w1c in fragment layout (global cols) ----
  float* sE1 = (float*)sA;              // [16][SFS] e1 plane (16.9 KB)
  float* sE2 = sE1 + 16*SFS;            // [16][SFS] e2 plane
  float w1c[RBF][2];
  #pragma unroll
  for (int nt = 0; nt < 2; ++nt){
    const int ng = nhalf*256 + ncol0 + nt*16 + rlo;
    #pragma unroll
    for (int r = 0; r < RBF; ++r) w1c[r][nt] = W1[r*HDIM + ng];
  }

  const int c4 = lane * 4;              // sweep: block-local col base
  const int gs = nhalf*256 + c4;        // sweep: global col base
  float* __restrict__ out2 = out + (size_t)E * HDIM;

  #pragma unroll
  for (int c = 0; c < 4; ++c){
    if (c) __syncthreads();             // prev sweeps done reading planes
    // scatter: fragment rows m = c*16 + kg*4 + r; e1 AND e2 computed HERE
    #pragma unroll
    for (int r = 0; r < 4; ++r){
      const int m  = c*16 + kg*4 + r;
      const int lr = kg*4 + r;          // local row 0..15
      const float* p0row = P0 + (size_t)sXi[m] * HDIM;
      const float* p1row = P1 + (size_t)sXj[m] * HDIM;
      float2 ra = *(const float2*)(sRbf + m*RBF);
      float2 rb = *(const float2*)(sRbf + m*RBF + 2);
      float2 rc = *(const float2*)(sRbf + m*RBF + 4);
      #pragma unroll
      for (int nt = 0; nt < 2; ++nt){
        const int nl = ncol0 + nt*16 + rlo;       // block-local col
        const int ng = nhalf*256 + nl;            // global col
        float f  = acc[c][nt][r] + p0row[ng] + p1row[ng];
        float e1 = swishf(f);
        float g  = ra.x*w1c[0][nt] + ra.y*w1c[1][nt] + rb.x*w1c[2][nt]
                 + rb.y*w1c[3][nt] + rc.x*w1c[4][nt] + rc.y*w1c[5][nt];
        sE1[lr*SFS + nl] = e1;
        sE2[lr*SFS + nl] = g * e1;
      }
    }
    __syncthreads();
    // sweeps: pure copies; wave = one row x 256 cols = 1KB per instruction
    #pragma unroll
    for (int j = 0; j < 2; ++j){
      const int lr = j*8 + w;
      const int m  = c*16 + lr;
      if (m < me){
        const size_t orow = (size_t)(eb + m) * HDIM + gs;
        f32x4 v1 = *(const f32x4*)(sE1 + lr*SFS + c4);
        *(f32x4*)(out  + orow) = v1;
        f32x4 v2 = *(const f32x4*)(sE2 + lr*SFS + c4);
        *(f32x4*)(out2 + orow) = v2;
      }
    }
  }
}

// ---------------------------------------------------------------------------
extern "C" void kernel_launch(void* const* d_in, const int* in_sizes, int n_in,
                              void* d_out, int out_size, void* d_ws, size_t ws_size,
                              hipStream_t stream) {
  const int*   xv    = (const int*)  d_in[0];
  const float* rbf   = (const float*)d_in[1];
  const int*   ei    = (const int*)  d_in[2];
  const int*   ej    = (const int*)  d_in[3];
  const float* emb   = (const float*)d_in[4];
  const float* W0    = (const float*)d_in[5];
  const float* b0    = (const float*)d_in[6];
  const float* W_lin = (const float*)d_in[7];
  const float* b_lin = (const float*)d_in[8];
  const float* W1    = (const float*)d_in[9];
  float* out = (float*)d_out;

  const int E = in_sizes[2];

  float* P0 = (float*)d_ws;
  float* P1 = P0 + NQ * HDIM;
  unsigned short* W2T = (unsigned short*)(P1 + NQ * HDIM);

  prep_tables<<<2 * NQ, 512, 0, stream>>>(emb, W_lin, b_lin, P0, P1);
  prep_w2t<<<(HDIM * (HDIM/8)) / 256, 256, 0, stream>>>(W_lin, W2T);

  const int nblk = (E + BM - 1) / BM;
  fused_edge<<<2 * nblk, 512, 0, stream>>>(xv, rbf, ei, ej, W0, b0, W1,
                                           P0, P1, W2T, out, E);
}

// Round 18
// 496.220 us; speedup vs baseline: 1.8074x; 1.1960x over previous
//
#include <hip/hip_runtime.h>
#include <hip/hip_bf16.h>

typedef __attribute__((ext_vector_type(8))) short short8;
typedef __attribute__((ext_vector_type(4))) float f32x4;

#define NQ 95
#define HDIM 512
#define RBF 6
#define BM 128

static __device__ __forceinline__ unsigned short f2bf(float f){
  unsigned u = __float_as_uint(f);
  u += 0x7FFF + ((u >> 16) & 1);          // round-to-nearest-even
  return (unsigned short)(u >> 16);
}
static __device__ __forceinline__ float swishf(float z){
  float e = __expf(-z);
  return z * __builtin_amdgcn_rcpf(1.0f + e);
}

// ---------------------------------------------------------------------------
// P0[v][n] = sum_k emb[v][k] * W_lin[k][n] + b_lin[n];  P1: second 512-block
// ---------------------------------------------------------------------------
__global__ __launch_bounds__(512) void prep_tables(
    const float* __restrict__ emb, const float* __restrict__ W_lin,
    const float* __restrict__ b_lin, float* __restrict__ P0,
    float* __restrict__ P1)
{
  __shared__ float sE[HDIM];
  const int v   = blockIdx.x % NQ;
  const int tab = blockIdx.x / NQ;
  const int t   = threadIdx.x;
  sE[t] = emb[v*HDIM + t];
  __syncthreads();
  const float* W = W_lin + (size_t)tab * HDIM * HDIM + t;
  float a = tab ? 0.f : b_lin[t];
  #pragma unroll 8
  for (int k = 0; k < HDIM; ++k)
    a += sE[k] * W[(size_t)k * HDIM];
  (tab ? P1 : P0)[v*HDIM + t] = a;
}

// ---------------------------------------------------------------------------
// W2T[n][k] = bf16(W_lin[1024+k][n])   (512x512 bf16, n-major)
// ---------------------------------------------------------------------------
__global__ __launch_bounds__(256) void prep_w2t(
    const float* __restrict__ W_lin, unsigned short* __restrict__ W2T)
{
  const int idx = blockIdx.x * 256 + threadIdx.x;
  const int n  = idx >> 6;
  const int kb = (idx & 63) * 8;
  const float* W2 = W_lin + (size_t)1024 * HDIM;
  unsigned p[4];
  #pragma unroll
  for (int c = 0; c < 4; ++c){
    unsigned lo = f2bf(W2[(size_t)(kb + 2*c    ) * HDIM + n]);
    unsigned hi = f2bf(W2[(size_t)(kb + 2*c + 1) * HDIM + n]);
    p[c] = lo | (hi << 16);
  }
  uint4 o; o.x = p[0]; o.y = p[1]; o.z = p[2]; o.w = p[3];
  *(uint4*)(W2T + (size_t)n * HDIM + kb) = o;
}

// ---------------------------------------------------------------------------
// Fused main kernel (champion R10 structure): 1024 threads (16 waves),
// BM=128 edges/block.
//   phase 1: A = bf16(swish(rbf@W0+b0)) [128x512] in LDS (XOR swizzle, 128KB)
//   phase 2: acc = A @ W2T, wave tile 128 rows x 32 cols (acc[8][2])
//   epilogue: 4 chunks x 32 rows — scatter raw acc into dead A-tile LDS,
//     then column-contiguous sweep: f32x4 coalesced wave-uniform P0/P1
//     gathers (1KB/instr), swish + g in sweep layout, f32x4 line stores.
// ---------------------------------------------------------------------------
__global__ __launch_bounds__(1024, 4) void fused_edge(
    const int* __restrict__ xv, const float* __restrict__ rbf,
    const int* __restrict__ ei, const int* __restrict__ ej,
    const float* __restrict__ W0, const float* __restrict__ b0,
    const float* __restrict__ W1,
    const float* __restrict__ P0, const float* __restrict__ P1,
    const unsigned short* __restrict__ W2T,
    float* __restrict__ out, int E)
{
  __shared__ unsigned short sA[BM * HDIM];   // 128 KB
  __shared__ float sRbf[BM * RBF];
  __shared__ int sXi[BM], sXj[BM];

  const int t  = threadIdx.x;
  const int eb = blockIdx.x * BM;
  const int me = min(BM, E - eb);

  // ---- stage rbf rows (128*6 = 192 float4) + node-type indices ----
  if (t < 192){
    float4 v = make_float4(0.f, 0.f, 0.f, 0.f);
    size_t gi  = (size_t)eb * RBF + (size_t)t * 4;
    size_t lim = (size_t)E * RBF;
    if (gi + 4 <= lim) v = *(const float4*)(rbf + gi);
    else {
      float* pv = (float*)&v;
      for (int c = 0; c < 4; ++c) if (gi + c < lim) pv[c] = rbf[gi + c];
    }
    *(float4*)(sRbf + t*4) = v;
  } else if (t >= 256 && t < 384){
    int q = t - 256;
    int xi = 0, xj = 0;
    int e = eb + q;
    if (e < E){ xi = xv[ei[e]]; xj = xv[ej[e]]; }
    sXi[q] = xi; sXj[q] = xj;
  }

  // phase-1 assignment: 256 col-pairs x 4 row-quarters (32 rows each)
  const int cp = t & 255;          // k-pair: cols 2cp, 2cp+1
  const int q4 = t >> 8;           // rows q4*32 .. q4*32+31
  float2 w0c[RBF];
  #pragma unroll
  for (int r = 0; r < RBF; ++r) w0c[r] = *(const float2*)(W0 + r*HDIM + 2*cp);
  float2 bb = *(const float2*)(b0 + 2*cp);

  __syncthreads();

  char* sAb = (char*)sA;
  // ---- phase 1: rbf0 tile ----
  {
    const int swz_t = 4 * cp;
    const int m0 = q4 * 32;
    #pragma unroll 2
    for (int mm = 0; mm < 32; ++mm){
      const int m = m0 + mm;
      float2 ra = *(const float2*)(sRbf + m*RBF);
      float2 rb = *(const float2*)(sRbf + m*RBF + 2);
      float2 rc = *(const float2*)(sRbf + m*RBF + 4);
      float z0 = bb.x, z1 = bb.y;
      z0 += ra.x*w0c[0].x + ra.y*w0c[1].x + rb.x*w0c[2].x
          + rb.y*w0c[3].x + rc.x*w0c[4].x + rc.y*w0c[5].x;
      z1 += ra.x*w0c[0].y + ra.y*w0c[1].y + rb.x*w0c[2].y
          + rb.y*w0c[3].y + rc.x*w0c[4].y + rc.y*w0c[5].y;
      unsigned pk = (unsigned)f2bf(swishf(z0)) | ((unsigned)f2bf(swishf(z1)) << 16);
      *(unsigned*)(sAb + (m*1024 + (swz_t ^ ((m & 7) << 4)))) = pk;
    }
  }
  __syncthreads();

  // ---- phase 2: MFMA K-loop (wave tile: 128 rows x 32 cols) ----
  const int lane  = t & 63;
  const int w     = t >> 6;        // 0..15
  const int nbase = w * 32;
  const int rlo   = lane & 15;
  const int kg    = lane >> 4;

  f32x4 acc[8][2];
  #pragma unroll
  for (int a = 0; a < 8; ++a)
    #pragma unroll
    for (int b = 0; b < 2; ++b) acc[a][b] = f32x4{0.f, 0.f, 0.f, 0.f};

  const unsigned short* bp0 = W2T + (size_t)(nbase + rlo)*HDIM + kg*8;
  const unsigned short* bp1 = bp0 + (size_t)16*HDIM;

  for (int ks = 0; ks < 16; ++ks){
    short8 b0r = *(const short8*)(bp0 + ks*32);
    short8 b1r = *(const short8*)(bp1 + ks*32);
    #pragma unroll
    for (int mt = 0; mt < 8; ++mt){
      int row = mt*16 + rlo;
      int off = row*1024 + ((ks*64 + kg*16) ^ ((row & 7) << 4));
      short8 af = *(const short8*)(sAb + off);
      acc[mt][0] = __builtin_amdgcn_mfma_f32_16x16x32_bf16(af, b0r, acc[mt][0], 0, 0, 0);
      acc[mt][1] = __builtin_amdgcn_mfma_f32_16x16x32_bf16(af, b1r, acc[mt][1], 0, 0, 0);
    }
  }

  __syncthreads();   // all waves done reading the A-tile -> sA is dead

  // ---- epilogue: 4 chunks x 32 rows; acc-repack; coalesced sweep ----
  float* sF = (float*)sA;              // 32 x 512 f32 = 64 KB (in dead A-tile)
  const int n0  = (4*t) & (HDIM - 1);  // fixed 4 output columns per thread
  const int rad = t >> 7;              // 0..7 (8 rows per sweep pass)

  f32x4 w1v[RBF];
  #pragma unroll
  for (int r = 0; r < RBF; ++r) w1v[r] = *(const f32x4*)(W1 + r*HDIM + n0);
  float* __restrict__ out2 = out + (size_t)E * HDIM;

  #pragma unroll
  for (int c = 0; c < 4; ++c){
    if (c) __syncthreads();            // prev sweep done reading sF
    // scatter: raw acc of rows 32c..32c+31 into sF (fragment layout write)
    #pragma unroll
    for (int mi = 0; mi < 2; ++mi){
      #pragma unroll
      for (int r = 0; r < 4; ++r){
        const int lr = mi*16 + kg*4 + r;       // local row 0..31
        #pragma unroll
        for (int nt = 0; nt < 2; ++nt){
          const int n = nbase + nt*16 + rlo;
          sF[lr*HDIM + n] = acc[2*c + mi][nt][r];
        }
      }
    }
    __syncthreads();
    // sweep: thread owns 4 contiguous cols of 8 rows per pass
    #pragma unroll
    for (int j = 0; j < 4; ++j){
      const int lm = j*8 + rad;
      const int m  = c*32 + lm;
      const bool valid = (m < me);
      const int xi = sXi[m], xj = sXj[m];      // wave-uniform row indices
      f32x4 a  = *(const f32x4*)(sF + lm*HDIM + n0);
      f32x4 p0 = *(const f32x4*)(P0 + (size_t)xi*HDIM + n0);
      f32x4 p1 = *(const f32x4*)(P1 + (size_t)xj*HDIM + n0);
      f32x4 f  = (a + p0) + p1;
      f32x4 e1;
      e1.x = swishf(f.x); e1.y = swishf(f.y);
      e1.z = swishf(f.z); e1.w = swishf(f.w);
      float2 ra = *(const float2*)(sRbf + m*RBF);
      float2 rb = *(const float2*)(sRbf + m*RBF + 2);
      float2 rc = *(const float2*)(sRbf + m*RBF + 4);
      f32x4 g;
      g.x = ra.x*w1v[0].x + ra.y*w1v[1].x + rb.x*w1v[2].x
          + rb.y*w1v[3].x + rc.x*w1v[4].x + rc.y*w1v[5].x;
      g.y = ra.x*w1v[0].y + ra.y*w1v[1].y + rb.x*w1v[2].y
          + rb.y*w1v[3].y + rc.x*w1v[4].y + rc.y*w1v[5].y;
      g.z = ra.x*w1v[0].z + ra.y*w1v[1].z + rb.x*w1v[2].z
          + rb.y*w1v[3].z + rc.x*w1v[4].z + rc.y*w1v[5].z;
      g.w = ra.x*w1v[0].w + ra.y*w1v[1].w + rb.x*w1v[2].w
          + rb.y*w1v[3].w + rc.x*w1v[4].w + rc.y*w1v[5].w;
      f32x4 e2 = g * e1;
      if (valid){
        const size_t orow = (size_t)(eb + m) * HDIM + n0;
        *(f32x4*)(out  + orow) = e1;
        *(f32x4*)(out2 + orow) = e2;
      }
    }
  }
}

// ---------------------------------------------------------------------------
extern "C" void kernel_launch(void* const* d_in, const int* in_sizes, int n_in,
                              void* d_out, int out_size, void* d_ws, size_t ws_size,
                              hipStream_t stream) {
  const int*   xv    = (const int*)  d_in[0];
  const float* rbf   = (const float*)d_in[1];
  const int*   ei    = (const int*)  d_in[2];
  const int*   ej    = (const int*)  d_in[3];
  const float* emb   = (const float*)d_in[4];
  const float* W0    = (const float*)d_in[5];
  const float* b0    = (const float*)d_in[6];
  const float* W_lin = (const float*)d_in[7];
  const float* b_lin = (const float*)d_in[8];
  const float* W1    = (const float*)d_in[9];
  float* out = (float*)d_out;

  const int E = in_sizes[2];

  float* P0 = (float*)d_ws;
  float* P1 = P0 + NQ * HDIM;
  unsigned short* W2T = (unsigned short*)(P1 + NQ * HDIM);

  prep_tables<<<2 * NQ, 512, 0, stream>>>(emb, W_lin, b_lin, P0, P1);
  prep_w2t<<<(HDIM * (HDIM/8)) / 256, 256, 0, stream>>>(W_lin, W2T);

  const int nblk = (E + BM - 1) / BM;
  fused_edge<<<nblk, 1024, 0, stream>>>(xv, rbf, ei, ej, W0, b0, W1,
                                        P0, P1, W2T, out, E);
}